// Round 1
// baseline (158.104 us; speedup 1.0000x reference)
//
#include <hip/hip_runtime.h>
#include <hip/hip_bf16.h>
#include <stdint.h>

typedef unsigned short u16;
typedef __attribute__((ext_vector_type(8))) short short8;   // 8 bf16 (4 VGPRs) MFMA A/B frag
typedef __attribute__((ext_vector_type(4))) float floatx4;  // MFMA C/D frag

#define M_TOT 16384   // B*S
#define N_OUT 2304
#define KX    768
#define KL    128     // E*R
#define SCALING 2.0f
#define NTILES 14     // K=896 / BK=64

// prep-kernel block regions (256 thr/blk, 8 elems/thr for cvt)
#define XBLKS   6144   // x: 16384*768/2048
#define WBLKS   864    // W: 2304*768/2048
#define ABLKS   48     // A: 128*768/2048
#define BMRBLKS 144    // bmr: 2304*128/2048
#define PREP_BLOCKS (XBLKS + WBLKS + ABLKS + BMRBLKS + 1)  // +1 gate block

__device__ __forceinline__ u16 f2b(float f) {
  union { __hip_bfloat16 h; u16 u; } c; c.h = __float2bfloat16(f); return c.u;
}
__device__ __forceinline__ float ldf(const void* p, long i, bool f32) {
  if (f32) return ((const float*)p)[i];
  union { u16 u; __hip_bfloat16 h; } c; c.u = ((const u16*)p)[i];
  return __bfloat162float(c.h);
}

__device__ __forceinline__ void gload_lds16(const void* g, void* l) {
  __builtin_amdgcn_global_load_lds(
      (const __attribute__((address_space(1))) void*)g,
      (__attribute__((address_space(3))) void*)l, 16, 0, 0);
}

// 8-element fp32/bf16 -> bf16 convert-copy, group index i
__device__ __forceinline__ void cvt8(const void* src, u16* dst, long i, bool f32) {
  u16 v[8];
  if (f32) {
    const float4* s = (const float4*)src;
    float4 a = s[i * 2], b = s[i * 2 + 1];
    v[0] = f2b(a.x); v[1] = f2b(a.y); v[2] = f2b(a.z); v[3] = f2b(a.w);
    v[4] = f2b(b.x); v[5] = f2b(b.y); v[6] = f2b(b.z); v[7] = f2b(b.w);
  } else {
    *(uint4*)v = ((const uint4*)src)[i];
  }
  ((uint4*)dst)[i] = *(uint4*)v;
}

// ---- prep: fused dtype-detect + cvt(x,W,A) + bmr build + gate softmax ----
__global__ __launch_bounds__(256) void prep_kernel(
    const void* __restrict__ x,  const void* __restrict__ W,
    const void* __restrict__ A,  const void* __restrict__ Bm,
    const void* __restrict__ z,  const void* __restrict__ Wg,
    const void* __restrict__ bg,
    u16* __restrict__ xbf, u16* __restrict__ Wbf, u16* __restrict__ Abf,
    u16* __restrict__ bmr, float* __restrict__ gsc, int* __restrict__ flagp) {
  __shared__ int s_flag;
  const int tid = threadIdx.x;
  // block-local dtype detect: even u16s of fp32 N(0,1) data are uniform mantissa
  // bits -> bf16-exp>=160 w.p. ~0.375; genuine bf16 N(0,1) never. (R2-verified)
  if (tid < 64) {
    u16 v = ((const u16*)x)[tid * 2];
    int e = (v >> 7) & 0xFF;
    int huge = (e >= 160) ? 1 : 0;
    for (int off = 1; off < 64; off <<= 1) huge += __shfl_xor(huge, off, 64);
    if (tid == 0) s_flag = (huge >= 4) ? 1 : 0;
  }
  __syncthreads();
  const bool f32 = (s_flag != 0);

  int b = blockIdx.x;
  if (b < XBLKS) {
    cvt8(x, xbf, (long)b * 256 + tid, f32);
  } else if (b < XBLKS + WBLKS) {
    cvt8(W, Wbf, (long)(b - XBLKS) * 256 + tid, f32);
  } else if (b < XBLKS + WBLKS + ABLKS) {
    cvt8(A, Abf, (long)(b - XBLKS - WBLKS) * 256 + tid, f32);
  } else if (b < XBLKS + WBLKS + ABLKS + BMRBLKS) {
    // Bm [E][2304][16] -> bmr [2304][128]
    long i0 = ((long)(b - XBLKS - WBLKS - ABLKS) * 256 + tid) * 8;
    u16 v[8];
#pragma unroll
    for (int j = 0; j < 8; ++j) {
      long idx = i0 + j;
      long o = idx >> 7, er = idx & 127;
      long e = er >> 4, r = er & 15;
      v[j] = f2b(ldf(Bm, (e * 2304 + o) * 16 + r, f32));
    }
    *(uint4*)&bmr[i0] = *(uint4*)v;
  } else {
    // gate: gsc[bb*8+e] = softmax_e(z[bb,:].Wg[e,:] + bg[e]) * SCALING
    if (tid == 0) *flagp = s_flag;
    if (tid < 64) {
      const int bb = tid >> 3, e = tid & 7;
      float acc = ldf(bg, e, f32);
      for (int i = 0; i < 64; ++i)
        acc += ldf(z, bb * 64 + i, f32) * ldf(Wg, e * 64 + i, f32);
      float mx = acc;
      for (int off = 1; off < 8; off <<= 1) mx = fmaxf(mx, __shfl_xor(mx, off, 64));
      float ex = __expf(acc - mx);
      float sm = ex;
      for (int off = 1; off < 8; off <<= 1) sm += __shfl_xor(sm, off, 64);
      gsc[tid] = (ex / sm) * SCALING;
    }
  }
}

// ---- gemm_h: hg[m, e*16+r] = (x @ A^T)[m,er] * gsc[batch(m)*8+e] ----
// M=16384, N=128, K=768; 128x128 tile, BK=64, m97 structure. bf16 out.
__global__ __launch_bounds__(256) void gemm_h(
    const u16* __restrict__ xbf, const u16* __restrict__ Abf,
    const float* __restrict__ gsc, u16* __restrict__ hg) {
  __shared__ __align__(128) u16 As[128][64];
  __shared__ __align__(128) u16 Bs[128][64];
  const int tid = threadIdx.x, wave = tid >> 6, lane = tid & 63;
  const int wm = wave >> 1, wn = wave & 1;
  const int quad = lane >> 4, l16 = lane & 15;
  const int srow = lane >> 3, scol = (lane & 7) * 8;
  const int m0 = blockIdx.x * 128;

  floatx4 acc[4][4];
#pragma unroll
  for (int i = 0; i < 4; ++i)
#pragma unroll
    for (int j = 0; j < 4; ++j) acc[i][j] = floatx4{0.f, 0.f, 0.f, 0.f};

  for (int kb = 0; kb < 12; ++kb) {
    const int kc = kb * 64;
#pragma unroll
    for (int j = 0; j < 4; ++j) {
      int r = wave * 32 + j * 8 + srow;
      gload_lds16(xbf + (size_t)(m0 + r) * KX + kc + scol,
                  (char*)(&As[0][0]) + (wave * 32 + j * 8) * 128);
      gload_lds16(Abf + (size_t)r * KX + kc + scol,
                  (char*)(&Bs[0][0]) + (wave * 32 + j * 8) * 128);
    }
    __syncthreads();
#pragma unroll
    for (int ks = 0; ks < 2; ++ks) {
      short8 af[4], bf[4];
#pragma unroll
      for (int mi = 0; mi < 4; ++mi)
        af[mi] = *(const short8*)&As[wm * 64 + mi * 16 + l16][ks * 32 + quad * 8];
#pragma unroll
      for (int ni = 0; ni < 4; ++ni)
        bf[ni] = *(const short8*)&Bs[wn * 64 + ni * 16 + l16][ks * 32 + quad * 8];
#pragma unroll
      for (int mi = 0; mi < 4; ++mi)
#pragma unroll
        for (int ni = 0; ni < 4; ++ni)
          acc[mi][ni] = __builtin_amdgcn_mfma_f32_16x16x32_bf16(af[mi], bf[ni], acc[mi][ni], 0, 0, 0);
    }
    __syncthreads();
  }
  // epilogue: scale by gate; e = col>>4 = wn*4+ni (col-block 16 = one expert)
  const int bb = m0 >> 11;
  float gv[4];
#pragma unroll
  for (int ni = 0; ni < 4; ++ni) gv[ni] = gsc[bb * 8 + wn * 4 + ni];
#pragma unroll
  for (int mi = 0; mi < 4; ++mi) {
    int rbase = m0 + wm * 64 + mi * 16 + quad * 4;
#pragma unroll
    for (int ni = 0; ni < 4; ++ni) {
      int c = wn * 64 + ni * 16 + l16;
#pragma unroll
      for (int t = 0; t < 4; ++t)
        hg[(size_t)(rbase + t) * KL + c] = f2b(acc[mi][ni][t] * gv[ni]);
    }
  }
}

// ==== gemm_main: 256x256-tile 8-phase template (T2 swizzle + T3/T4 counted
// vmcnt + T5 setprio). out = [x | hg] @ [W | bmr]^T + b; M=16384 N=2304 K=896.
// 512 thr (8 waves, 2M x 4N), BK=64, LDS 128KiB (2 dbuf x 32KB x {A,B}).
// Per K-tile 4 phases; stages stream 1 half-tile/phase:
//   p1:(t+1)A1  p2:(t+1)B1  p3:(t+2)B0  p4:(t+2)A0
// Overwrite deadlines (verified vs read schedule): A-reads done by p2 (< p4
// stage into buf.A0 — other-buf A1 untouched this tile), B-reads done by p2
// (< p3 stage into buf.B0); each phase's lgkmcnt(0)+barrier drains before the
// next phase's stage issues. vmcnt(4) at tile end leaves exactly the p3/p4
// stages in flight (never drain to 0 in steady state).

#define KX2 1536   // xbf/Wbf row stride bytes
#define KL2 256    // hg/bmr row stride bytes

// LDS XOR swizzle: 16B-chunk permute within 8-row x 128B stripe (G4 attn fix).
// Both-sides-or-neither (rule #21): gload_lds dest stays LINEAR; the inverse
// permutation is applied to the per-lane GLOBAL source address; ds_read
// applies the same XOR on the read address.
__device__ __forceinline__ void stage_half(const u16* src, int ldab, int row0,
                                           int kcb, char* ldsTile, int half,
                                           int wave, int lane) {
#pragma unroll
  for (int j = 0; j < 2; ++j) {
    const int chunk = half * 16384 + (wave * 2 + j) * 1024;
    const int q = chunk + lane * 16;                 // linear byte in 32KB tile
    const int row = q >> 7;
    const int col = (q & 127) ^ ((row & 7) << 4);    // pre-swizzled source col
    gload_lds16((const char*)src + (size_t)(row0 + row) * ldab + kcb + col,
                ldsTile + chunk);                    // uniform base + lane*16
  }
}

__device__ __forceinline__ short8 ldfrag(const char* tile, int row, int colb) {
  return *(const short8*)(tile + row * 128 + (colb ^ ((row & 7) << 4)));
}

#define MFMA16(a, b, c) __builtin_amdgcn_mfma_f32_16x16x32_bf16(a, b, c, 0, 0, 0)
#define BAR() __builtin_amdgcn_s_barrier()
#define LGKM0() asm volatile("s_waitcnt lgkmcnt(0)" ::: "memory")

template <int BUF>
__device__ __forceinline__ void tile_step(
    int t, const u16* xbf, const u16* hg, const u16* Wbf, const u16* bmr,
    int m0, int n0, int wave, int lane, int wm, int wn, int quad, int l16,
    char* As0, char* Bs0, floatx4 (&acc)[8][4]) {
  char* At = As0 + BUF * 32768;
  char* Bt = Bs0 + BUF * 32768;
  char* Ao = As0 + (BUF ^ 1) * 32768;
  char* Bo = Bs0 + (BUF ^ 1) * 32768;
  const bool stg1 = (t + 1 < NTILES), stg2 = (t + 2 < NTILES);
  // staged-tile sources (composite K: tiles 0..11 from x/W, 12..13 from hg/bmr)
  const u16 *a1p = xbf, *b1p = Wbf, *a2p = xbf, *b2p = Wbf;
  int lda1 = KX2, ldb1 = KX2, kc1 = (t + 1) * 128;
  int lda2 = KX2, ldb2 = KX2, kc2 = (t + 2) * 128;
  if (t + 1 >= 12) { a1p = hg; b1p = bmr; lda1 = KL2; ldb1 = KL2; kc1 = (t + 1 - 12) * 128; }
  if (t + 2 >= 12) { a2p = hg; b2p = bmr; lda2 = KL2; ldb2 = KL2; kc2 = (t + 2 - 12) * 128; }
  const int arow = wm * 128, brow = wn * 64;

  short8 a[8], b0[4], b1[4];

  // ---- phase 1: read A[*][ks0] (8) + B[0,1][ks0] (2); stage (t+1)A1
#pragma unroll
  for (int mi = 0; mi < 8; ++mi) a[mi] = ldfrag(At, arow + mi * 16 + l16, quad * 16);
  b0[0] = ldfrag(Bt, brow + l16, quad * 16);
  b0[1] = ldfrag(Bt, brow + 16 + l16, quad * 16);
  if (stg1) stage_half(a1p, lda1, m0, kc1, Ao, 1, wave, lane);
  BAR(); LGKM0();
  __builtin_amdgcn_s_setprio(1);
#pragma unroll
  for (int mi = 0; mi < 8; ++mi) {
    acc[mi][0] = MFMA16(a[mi], b0[0], acc[mi][0]);
    acc[mi][1] = MFMA16(a[mi], b0[1], acc[mi][1]);
  }
  __builtin_amdgcn_s_setprio(0);
  BAR();

  // ---- phase 2: read B[2,3][ks0] (2) + B[*][ks1] (4); stage (t+1)B1
  b0[2] = ldfrag(Bt, brow + 32 + l16, quad * 16);
  b0[3] = ldfrag(Bt, brow + 48 + l16, quad * 16);
#pragma unroll
  for (int ni = 0; ni < 4; ++ni)
    b1[ni] = ldfrag(Bt, brow + ni * 16 + l16, 64 + quad * 16);
  if (stg1) stage_half(b1p, ldb1, n0, kc1, Bo, 1, wave, lane);
  BAR(); LGKM0();
  __builtin_amdgcn_s_setprio(1);
#pragma unroll
  for (int mi = 0; mi < 8; ++mi) {
    acc[mi][2] = MFMA16(a[mi], b0[2], acc[mi][2]);
    acc[mi][3] = MFMA16(a[mi], b0[3], acc[mi][3]);
  }
  __builtin_amdgcn_s_setprio(0);
  BAR();

  // ---- phase 3: read A[*][ks1] (8); stage (t+2)B0 (B-reads all drained)
#pragma unroll
  for (int mi = 0; mi < 8; ++mi) a[mi] = ldfrag(At, arow + mi * 16 + l16, 64 + quad * 16);
  if (stg2) stage_half(b2p, ldb2, n0, kc2, Bt, 0, wave, lane);
  BAR(); LGKM0();
  __builtin_amdgcn_s_setprio(1);
#pragma unroll
  for (int mi = 0; mi < 8; ++mi) {
    acc[mi][0] = MFMA16(a[mi], b1[0], acc[mi][0]);
    acc[mi][1] = MFMA16(a[mi], b1[1], acc[mi][1]);
  }
  __builtin_amdgcn_s_setprio(0);
  BAR();

  // ---- phase 4: no reads; stage (t+2)A0 (A-reads all drained); counted vmcnt
  if (stg2) stage_half(a2p, lda2, m0, kc2, At, 0, wave, lane);
  BAR();
  __builtin_amdgcn_s_setprio(1);
#pragma unroll
  for (int mi = 0; mi < 8; ++mi) {
    acc[mi][2] = MFMA16(a[mi], b1[2], acc[mi][2]);
    acc[mi][3] = MFMA16(a[mi], b1[3], acc[mi][3]);
  }
  __builtin_amdgcn_s_setprio(0);
  // tile t+1 fully landed after this wait; p3/p4 stages stay in flight
  if (stg2) asm volatile("s_waitcnt vmcnt(4)" ::: "memory");
  else      asm volatile("s_waitcnt vmcnt(0)" ::: "memory");
  BAR();
}

__global__ __launch_bounds__(512, 2) void gemm_main(
    const u16* __restrict__ xbf, const u16* __restrict__ hg,
    const u16* __restrict__ Wbf, const u16* __restrict__ bmr,
    const void* __restrict__ bias, void* __restrict__ outv,
    const int* __restrict__ flagp) {
  __shared__ __align__(1024) u16 As[2][16384];   // 2 x 32KB: [256 rows][64 k] bf16
  __shared__ __align__(1024) u16 Bs[2][16384];

  const int tid = threadIdx.x, wave = tid >> 6, lane = tid & 63;
  const int wm = wave >> 2, wn = wave & 3;        // 2M x 4N waves
  const int quad = lane >> 4, l16 = lane & 15;

  // XCD-aware swizzle: 576 blocks = 8 xcd * (8 m-tiles * 9 n-tiles), bijective
  const int bid = blockIdx.x;
  const int xcd = bid & 7, g = bid >> 3;
  const int m0 = (xcd * 8 + (g & 7)) * 256;
  const int n0 = (g >> 3) * 256;

  char* As0 = (char*)&As[0][0];
  char* Bs0 = (char*)&Bs[0][0];

  floatx4 acc[8][4];
#pragma unroll
  for (int i = 0; i < 8; ++i)
#pragma unroll
    for (int j = 0; j < 4; ++j) acc[i][j] = floatx4{0.f, 0.f, 0.f, 0.f};

  // prologue: tile0 {A0,B0,A1,B1} then tile1 {B0,A0}; vmcnt(4) keeps tile1's
  // two halves in flight; barrier publishes tile0 to all waves.
  stage_half(xbf, KX2, m0, 0, As0, 0, wave, lane);
  stage_half(Wbf, KX2, n0, 0, Bs0, 0, wave, lane);
  stage_half(xbf, KX2, m0, 0, As0, 1, wave, lane);
  stage_half(Wbf, KX2, n0, 0, Bs0, 1, wave, lane);
  stage_half(Wbf, KX2, n0, 128, Bs0 + 32768, 0, wave, lane);
  stage_half(xbf, KX2, m0, 128, As0 + 32768, 0, wave, lane);
  asm volatile("s_waitcnt vmcnt(4)" ::: "memory");
  BAR();

#pragma unroll 1
  for (int tt = 0; tt < 7; ++tt) {
    tile_step<0>(tt * 2,     xbf, hg, Wbf, bmr, m0, n0, wave, lane, wm, wn, quad, l16, As0, Bs0, acc);
    tile_step<1>(tt * 2 + 1, xbf, hg, Wbf, bmr, m0, n0, wave, lane, wm, wn, quad, l16, As0, Bs0, acc);
  }

  // epilogue: C/D row = quad*4+t, col = l16 (m89/m91). Nontemporal stores:
  // output is write-once, never re-read -> avoid read-for-ownership fetch.
  const bool f32 = (*flagp != 0);
  float bv[4];
#pragma unroll
  for (int ni = 0; ni < 4; ++ni)
    bv[ni] = ldf(bias, n0 + wn * 64 + ni * 16 + l16, f32);
#pragma unroll
  for (int mi = 0; mi < 8; ++mi) {
    int rbase = m0 + wm * 128 + mi * 16 + quad * 4;
#pragma unroll
    for (int ni = 0; ni < 4; ++ni) {
      int c = n0 + wn * 64 + ni * 16 + l16;
#pragma unroll
      for (int u = 0; u < 4; ++u) {
        float v = acc[mi][ni][u] + bv[ni];
        size_t idx = (size_t)(rbase + u) * N_OUT + c;
        if (f32) __builtin_nontemporal_store(v, (float*)outv + idx);
        else     __builtin_nontemporal_store(f2b(v), (u16*)outv + idx);
      }
    }
  }
}

extern "C" void kernel_launch(void* const* d_in, const int* in_sizes, int n_in,
                              void* d_out, int out_size, void* d_ws, size_t ws_size,
                              hipStream_t stream) {
  // setup order: x, z, W, b, A, Bm, Wg, bg
  const void* x  = d_in[0];
  const void* z  = d_in[1];
  const void* W  = d_in[2];
  const void* bb = d_in[3];
  const void* A  = d_in[4];
  const void* Bm = d_in[5];
  const void* Wg = d_in[6];
  const void* bg = d_in[7];

  char* ws = (char*)d_ws;
  int*   flag = (int*)ws;
  float* gsc  = (float*)(ws + 256);
  u16*   xbf  = (u16*)(ws + 1024);                                   // 16384*768
  u16*   Wbf  = (u16*)(ws + 1024 + 25165824ull);                     // 2304*768
  u16*   Abf  = (u16*)(ws + 1024 + 25165824ull + 3538944ull);        // 128*768
  u16*   bmr  = (u16*)(ws + 1024 + 25165824ull + 3538944ull + 196608ull);
  u16*   hg   = (u16*)(ws + 1024 + 25165824ull + 3538944ull + 196608ull + 589824ull);

  prep_kernel<<<PREP_BLOCKS, 256, 0, stream>>>(
      x, W, A, Bm, z, Wg, bg, xbf, Wbf, Abf, bmr, gsc, flag);

  gemm_h<<<M_TOT / 128, 256, 0, stream>>>(xbf, Abf, gsc, hg);

  gemm_main<<<(N_OUT / 256) * (M_TOT / 256), 512, 0, stream>>>(
      xbf, hg, Wbf, bmr, bb, d_out, flag);
}

// Round 2
// 152.624 us; speedup vs baseline: 1.0359x; 1.0359x over previous
//
#include <hip/hip_runtime.h>
#include <hip/hip_bf16.h>
#include <stdint.h>

typedef unsigned short u16;
typedef __attribute__((ext_vector_type(8))) short short8;   // 8 bf16 (4 VGPRs) MFMA A/B frag
typedef __attribute__((ext_vector_type(4))) float floatx4;  // MFMA C/D frag

#define M_TOT 16384   // B*S
#define N_OUT 2304
#define KX    768
#define KL    128     // E*R
#define SCALING 2.0f

// prep-kernel block regions (256 thr/blk, 8 elems/thr)
#define XBLKS   6144   // x: 16384*768/2048
#define WBLKS   864    // W: 2304*768/2048
#define ABLKS   48     // Atr: 128*768/2048 (transposed A)
#define BMRBLKS 144    // bmr: 2304*128/2048
#define PREP_BLOCKS (XBLKS + WBLKS + ABLKS + BMRBLKS + 1)  // +1 gate block

__device__ __forceinline__ u16 f2b(float f) {
  union { __hip_bfloat16 h; u16 u; } c; c.h = __float2bfloat16(f); return c.u;
}
__device__ __forceinline__ float b2f(u16 u) {
  union { u16 u; __hip_bfloat16 h; } c; c.u = u;
  return __bfloat162float(c.h);
}
__device__ __forceinline__ float ldf(const void* p, long i, bool f32) {
  if (f32) return ((const float*)p)[i];
  return b2f(((const u16*)p)[i]);
}

__device__ __forceinline__ void gload_lds16(const void* g, void* l) {
  __builtin_amdgcn_global_load_lds(
      (const __attribute__((address_space(1))) void*)g,
      (__attribute__((address_space(3))) void*)l, 16, 0, 0);
}

// 8-element fp32/bf16 -> bf16 convert-copy, group index i
__device__ __forceinline__ void cvt8(const void* src, u16* dst, long i, bool f32) {
  u16 v[8];
  if (f32) {
    const float4* s = (const float4*)src;
    float4 a = s[i * 2], b = s[i * 2 + 1];
    v[0] = f2b(a.x); v[1] = f2b(a.y); v[2] = f2b(a.z); v[3] = f2b(a.w);
    v[4] = f2b(b.x); v[5] = f2b(b.y); v[6] = f2b(b.z); v[7] = f2b(b.w);
  } else {
    *(uint4*)v = ((const uint4*)src)[i];
  }
  ((uint4*)dst)[i] = *(uint4*)v;
}

// ---- prep: fused dtype-detect + cvt(x,W) + Atr transpose + bmr build + gate ----
__global__ __launch_bounds__(256) void prep_kernel(
    const void* __restrict__ x,  const void* __restrict__ W,
    const void* __restrict__ A,  const void* __restrict__ Bm,
    const void* __restrict__ z,  const void* __restrict__ Wg,
    const void* __restrict__ bg,
    u16* __restrict__ xbf, u16* __restrict__ Wbf, u16* __restrict__ Atr,
    u16* __restrict__ bmr, float* __restrict__ gsc, int* __restrict__ flagp) {
  __shared__ int s_flag;
  const int tid = threadIdx.x;
  // block-local dtype detect: even u16s of fp32 N(0,1) data are uniform mantissa
  // bits -> bf16-exp>=160 w.p. ~0.375; genuine bf16 N(0,1) never. (R2-verified)
  if (tid < 64) {
    u16 v = ((const u16*)x)[tid * 2];
    int e = (v >> 7) & 0xFF;
    int huge = (e >= 160) ? 1 : 0;
    for (int off = 1; off < 64; off <<= 1) huge += __shfl_xor(huge, off, 64);
    if (tid == 0) s_flag = (huge >= 4) ? 1 : 0;
  }
  __syncthreads();
  const bool f32 = (s_flag != 0);

  int b = blockIdx.x;
  if (b < XBLKS) {
    cvt8(x, xbf, (long)b * 256 + tid, f32);
  } else if (b < XBLKS + WBLKS) {
    cvt8(W, Wbf, (long)(b - XBLKS) * 256 + tid, f32);
  } else if (b < XBLKS + WBLKS + ABLKS) {
    // A [E][R][768] = [er][768] -> Atr [768][128] (er = e*16+r)
    long c0 = (long)(b - XBLKS - WBLKS) * 256 + tid;  // chunk: 8 i's of one er
    long er = c0 / 96, i0 = (c0 % 96) * 8;
    u16 v[8];
#pragma unroll
    for (int j = 0; j < 8; ++j) v[j] = f2b(ldf(A, er * 768 + i0 + j, f32));
#pragma unroll
    for (int j = 0; j < 8; ++j) Atr[(i0 + j) * 128 + er] = v[j];
  } else if (b < XBLKS + WBLKS + ABLKS + BMRBLKS) {
    // Bm [E][2304][16] -> bmr [2304][128]
    long i0 = ((long)(b - XBLKS - WBLKS - ABLKS) * 256 + tid) * 8;
    u16 v[8];
#pragma unroll
    for (int j = 0; j < 8; ++j) {
      long idx = i0 + j;
      long o = idx >> 7, er = idx & 127;
      long e = er >> 4, r = er & 15;
      v[j] = f2b(ldf(Bm, (e * 2304 + o) * 16 + r, f32));
    }
    *(uint4*)&bmr[i0] = *(uint4*)v;
  } else {
    // gate: gsc[bb*8+e] = softmax_e(z[bb,:].Wg[e,:] + bg[e]) * SCALING
    if (tid == 0) *flagp = s_flag;
    if (tid < 64) {
      const int bb = tid >> 3, e = tid & 7;
      float acc = ldf(bg, e, f32);
      for (int i = 0; i < 64; ++i)
        acc += ldf(z, bb * 64 + i, f32) * ldf(Wg, e * 64 + i, f32);
      float mx = acc;
      for (int off = 1; off < 8; off <<= 1) mx = fmaxf(mx, __shfl_xor(mx, off, 64));
      float ex = __expf(acc - mx);
      float sm = ex;
      for (int off = 1; off < 8; off <<= 1) sm += __shfl_xor(sm, off, 64);
      gsc[tid] = (ex / sm) * SCALING;
    }
  }
}

// ---- wcomb: Wcomb[b][o][i] = bf16( Wbf[o][i] + sum_k bmr[o][k]*gsc[b,k>>4]*Atr[i][k] )
// 8 batches x (M=2304 o) x (N=768 i), K=128. Grid ((b*18+mt)*6+nt), 128x128 tile,
// BK=64 (2 k-steps). A=bmr via gload_lds; B=Atr reg-staged with gate scale.
__global__ __launch_bounds__(256) void wcomb_kernel(
    const u16* __restrict__ bmr, const u16* __restrict__ Atr,
    const u16* __restrict__ Wbf, const float* __restrict__ gsc,
    u16* __restrict__ wc) {
  __shared__ __align__(128) u16 As[128][64];
  __shared__ __align__(128) u16 Bs[128][64];
  __shared__ float sg[8];
  const int tid = threadIdx.x, wave = tid >> 6, lane = tid & 63;
  const int wm = wave >> 1, wn = wave & 1;
  const int quad = lane >> 4, l16 = lane & 15;
  const int srow = lane >> 3, scol = (lane & 7) * 8;

  int bid = blockIdx.x;
  const int nt = bid % 6; bid /= 6;
  const int mt = bid % 18; const int b = bid / 18;
  const int m0 = mt * 128, n0 = nt * 128;

  if (tid < 8) sg[tid] = gsc[b * 8 + tid];
  __syncthreads();

  floatx4 acc[4][4];
#pragma unroll
  for (int i = 0; i < 4; ++i)
#pragma unroll
    for (int j = 0; j < 4; ++j) acc[i][j] = floatx4{0.f, 0.f, 0.f, 0.f};

  for (int kb = 0; kb < 2; ++kb) {
    const int kc = kb * 64;
    // A: bmr rows (o), ld=128
#pragma unroll
    for (int j = 0; j < 4; ++j) {
      int r = wave * 32 + j * 8 + srow;
      gload_lds16(bmr + (size_t)(m0 + r) * 128 + kc + scol,
                  (char*)(&As[0][0]) + (wave * 32 + j * 8) * 128);
    }
    // B: Atr rows (i), ld=128, scaled by gate g[k>>4] (uniform per 8-chunk)
#pragma unroll
    for (int j = 0; j < 4; ++j) {
      int c = j * 256 + tid;
      int row = c >> 3, ch = c & 7;
      u16 v[8];
      *(uint4*)v = *(const uint4*)&Atr[(size_t)(n0 + row) * 128 + kc + ch * 8];
      float g = sg[(kc + ch * 8) >> 4];
#pragma unroll
      for (int t = 0; t < 8; ++t) v[t] = f2b(b2f(v[t]) * g);
      *(uint4*)&Bs[row][ch * 8] = *(uint4*)v;
    }
    __syncthreads();
#pragma unroll
    for (int ks = 0; ks < 2; ++ks) {
      short8 af[4], bf[4];
#pragma unroll
      for (int mi = 0; mi < 4; ++mi)
        af[mi] = *(const short8*)&As[wm * 64 + mi * 16 + l16][ks * 32 + quad * 8];
#pragma unroll
      for (int ni = 0; ni < 4; ++ni)
        bf[ni] = *(const short8*)&Bs[wn * 64 + ni * 16 + l16][ks * 32 + quad * 8];
#pragma unroll
      for (int mi = 0; mi < 4; ++mi)
#pragma unroll
        for (int ni = 0; ni < 4; ++ni)
          acc[mi][ni] = __builtin_amdgcn_mfma_f32_16x16x32_bf16(af[mi], bf[ni], acc[mi][ni], 0, 0, 0);
    }
    __syncthreads();
  }
  // epilogue: add frozen W (bf16) and store Wcomb[b]
  u16* wcb = wc + (size_t)b * N_OUT * KX;
#pragma unroll
  for (int mi = 0; mi < 4; ++mi) {
    int rbase = m0 + wm * 64 + mi * 16 + quad * 4;
#pragma unroll
    for (int ni = 0; ni < 4; ++ni) {
      int c = n0 + wn * 64 + ni * 16 + l16;
#pragma unroll
      for (int t = 0; t < 4; ++t) {
        float v = acc[mi][ni][t] + b2f(Wbf[(size_t)(rbase + t) * KX + c]);
        wcb[(size_t)(rbase + t) * KX + c] = f2b(v);
      }
    }
  }
}

// ---- gemm_main: out[b] = x[b] @ Wcomb[b]^T + bias ; M=16384 N=2304 K=768 ----
// R0-proven 128x128-tile m97 structure; single K-source, 12 k-steps.
__global__ __launch_bounds__(256) void gemm_main(
    const u16* __restrict__ xbf, const u16* __restrict__ wc,
    const void* __restrict__ bias, void* __restrict__ outv,
    const int* __restrict__ flagp) {
  __shared__ __align__(128) u16 As[128][64];
  __shared__ __align__(128) u16 Bs[128][64];
  const int tid = threadIdx.x, wave = tid >> 6, lane = tid & 63;
  const int wm = wave >> 1, wn = wave & 1;
  const int quad = lane >> 4, l16 = lane & 15;
  const int srow = lane >> 3, scol = (lane & 7) * 8;

  // XCD-aware swizzle: 2304 blocks = 8 xcd * (16 m-tiles * 18 n-tiles);
  // xcd == batch: each XCD's B-set is exactly its Wcomb[b] (3.5MB, fits L2)
  const int linear = blockIdx.x;
  const int xcd = linear & 7;
  const int g = linear >> 3;            // 0..287
  const int m_idx = xcd * 16 + (g & 15);
  const int n_idx = g >> 4;             // 0..17
  const int m0 = m_idx * 128;
  const int n0 = n_idx * 128;
  const u16* wcb = wc + (size_t)(m0 >> 11) * N_OUT * KX;  // batch slice

  floatx4 acc[4][4];
#pragma unroll
  for (int i = 0; i < 4; ++i)
#pragma unroll
    for (int j = 0; j < 4; ++j) acc[i][j] = floatx4{0.f, 0.f, 0.f, 0.f};

  for (int kb = 0; kb < 12; ++kb) {
    const int kc = kb * 64;
#pragma unroll
    for (int j = 0; j < 4; ++j) {
      int r = wave * 32 + j * 8 + srow;
      gload_lds16(xbf + (size_t)(m0 + r) * KX + kc + scol,
                  (char*)(&As[0][0]) + (wave * 32 + j * 8) * 128);
      gload_lds16(wcb + (size_t)(n0 + r) * KX + kc + scol,
                  (char*)(&Bs[0][0]) + (wave * 32 + j * 8) * 128);
    }
    __syncthreads();
#pragma unroll
    for (int ks = 0; ks < 2; ++ks) {
      short8 af[4], bf[4];
#pragma unroll
      for (int mi = 0; mi < 4; ++mi)
        af[mi] = *(const short8*)&As[wm * 64 + mi * 16 + l16][ks * 32 + quad * 8];
#pragma unroll
      for (int ni = 0; ni < 4; ++ni)
        bf[ni] = *(const short8*)&Bs[wn * 64 + ni * 16 + l16][ks * 32 + quad * 8];
#pragma unroll
      for (int mi = 0; mi < 4; ++mi)
#pragma unroll
        for (int ni = 0; ni < 4; ++ni)
          acc[mi][ni] = __builtin_amdgcn_mfma_f32_16x16x32_bf16(af[mi], bf[ni], acc[mi][ni], 0, 0, 0);
    }
    __syncthreads();
  }

  // epilogue: C/D row = quad*4+t, col = l16 (m89/m91). Nontemporal stores:
  // output is write-once, never re-read -> avoid read-for-ownership fetch.
  const bool f32 = (*flagp != 0);
  float bv[4];
#pragma unroll
  for (int ni = 0; ni < 4; ++ni)
    bv[ni] = ldf(bias, n0 + wn * 64 + ni * 16 + l16, f32);
#pragma unroll
  for (int mi = 0; mi < 4; ++mi) {
    int rbase = m0 + wm * 64 + mi * 16 + quad * 4;
#pragma unroll
    for (int ni = 0; ni < 4; ++ni) {
      int c = n0 + wn * 64 + ni * 16 + l16;
#pragma unroll
      for (int t = 0; t < 4; ++t) {
        float v = acc[mi][ni][t] + bv[ni];
        size_t idx = (size_t)(rbase + t) * N_OUT + c;
        if (f32) __builtin_nontemporal_store(v, (float*)outv + idx);
        else     __builtin_nontemporal_store(f2b(v), (u16*)outv + idx);
      }
    }
  }
}

extern "C" void kernel_launch(void* const* d_in, const int* in_sizes, int n_in,
                              void* d_out, int out_size, void* d_ws, size_t ws_size,
                              hipStream_t stream) {
  // setup order: x, z, W, b, A, Bm, Wg, bg
  const void* x  = d_in[0];
  const void* z  = d_in[1];
  const void* W  = d_in[2];
  const void* bb = d_in[3];
  const void* A  = d_in[4];
  const void* Bm = d_in[5];
  const void* Wg = d_in[6];
  const void* bg = d_in[7];

  char* ws = (char*)d_ws;
  int*   flag = (int*)ws;
  float* gsc  = (float*)(ws + 256);
  u16*   xbf  = (u16*)(ws + 1024);                       // 16384*768*2 = 25165824
  u16*   Wbf  = (u16*)(ws + 1024 + 25165824ull);         // 2304*768*2  = 3538944
  u16*   Atr  = (u16*)(ws + 1024 + 25165824ull + 3538944ull);             // 196608
  u16*   bmr  = (u16*)(ws + 1024 + 25165824ull + 3538944ull + 196608ull); // 589824
  u16*   wcp  = (u16*)(ws + 1024 + 25165824ull + 3538944ull + 196608ull + 589824ull); // 8*3538944

  prep_kernel<<<PREP_BLOCKS, 256, 0, stream>>>(
      x, W, A, Bm, z, Wg, bg, xbf, Wbf, Atr, bmr, gsc, flag);

  wcomb_kernel<<<8 * 18 * 6, 256, 0, stream>>>(bmr, Atr, Wbf, gsc, wcp);

  gemm_main<<<(N_OUT / 128) * (M_TOT / 128), 256, 0, stream>>>(
      xbf, wcp, bb, d_out, flag);
}

// Round 3
// 128.061 us; speedup vs baseline: 1.2346x; 1.1918x over previous
//
#include <hip/hip_runtime.h>
#include <hip/hip_bf16.h>
#include <stdint.h>

typedef unsigned short u16;
typedef __attribute__((ext_vector_type(8))) short short8;   // 8 bf16 (4 VGPRs) MFMA A/B frag
typedef __attribute__((ext_vector_type(4))) float floatx4;  // MFMA C/D frag

#define M_TOT 16384   // B*S
#define N_OUT 2304
#define KX    768
#define KL    128     // E*R
#define SCALING 2.0f

// prep-kernel block regions (256 thr/blk, 8 elems/thr for cvt)
#define XBLKS   6144   // x: 16384*768/2048
#define WBLKS   864    // W: 2304*768/2048
#define ABLKS   48     // A: 128*768/2048
#define BMRBLKS 144    // bmr: 2304*128/2048
#define PREP_BLOCKS (XBLKS + WBLKS + ABLKS + BMRBLKS + 1)  // +1 gate block

__device__ __forceinline__ u16 f2b(float f) {
  union { __hip_bfloat16 h; u16 u; } c; c.h = __float2bfloat16(f); return c.u;
}
__device__ __forceinline__ float ldf(const void* p, long i, bool f32) {
  if (f32) return ((const float*)p)[i];
  union { u16 u; __hip_bfloat16 h; } c; c.u = ((const u16*)p)[i];
  return __bfloat162float(c.h);
}

__device__ __forceinline__ void gload_lds16(const void* g, void* l) {
  __builtin_amdgcn_global_load_lds(
      (const __attribute__((address_space(1))) void*)g,
      (__attribute__((address_space(3))) void*)l, 16, 0, 0);
}

// 8-element fp32/bf16 -> bf16 convert-copy, group index i
__device__ __forceinline__ void cvt8(const void* src, u16* dst, long i, bool f32) {
  u16 v[8];
  if (f32) {
    const float4* s = (const float4*)src;
    float4 a = s[i * 2], b = s[i * 2 + 1];
    v[0] = f2b(a.x); v[1] = f2b(a.y); v[2] = f2b(a.z); v[3] = f2b(a.w);
    v[4] = f2b(b.x); v[5] = f2b(b.y); v[6] = f2b(b.z); v[7] = f2b(b.w);
  } else {
    *(uint4*)v = ((const uint4*)src)[i];
  }
  ((uint4*)dst)[i] = *(uint4*)v;
}

// ---- prep: fused dtype-detect + cvt(x,W,A) + bmr build + gate softmax ----
__global__ __launch_bounds__(256) void prep_kernel(
    const void* __restrict__ x,  const void* __restrict__ W,
    const void* __restrict__ A,  const void* __restrict__ Bm,
    const void* __restrict__ z,  const void* __restrict__ Wg,
    const void* __restrict__ bg,
    u16* __restrict__ xbf, u16* __restrict__ Wbf, u16* __restrict__ Abf,
    u16* __restrict__ bmr, float* __restrict__ gsc, int* __restrict__ flagp) {
  __shared__ int s_flag;
  const int tid = threadIdx.x;
  // block-local dtype detect: even u16s of fp32 N(0,1) data are uniform mantissa
  // bits -> bf16-exp>=160 w.p. ~0.375; genuine bf16 N(0,1) never. (R2-verified)
  if (tid < 64) {
    u16 v = ((const u16*)x)[tid * 2];
    int e = (v >> 7) & 0xFF;
    int huge = (e >= 160) ? 1 : 0;
    for (int off = 1; off < 64; off <<= 1) huge += __shfl_xor(huge, off, 64);
    if (tid == 0) s_flag = (huge >= 4) ? 1 : 0;
  }
  __syncthreads();
  const bool f32 = (s_flag != 0);

  int b = blockIdx.x;
  if (b < XBLKS) {
    cvt8(x, xbf, (long)b * 256 + tid, f32);
  } else if (b < XBLKS + WBLKS) {
    cvt8(W, Wbf, (long)(b - XBLKS) * 256 + tid, f32);
  } else if (b < XBLKS + WBLKS + ABLKS) {
    cvt8(A, Abf, (long)(b - XBLKS - WBLKS) * 256 + tid, f32);
  } else if (b < XBLKS + WBLKS + ABLKS + BMRBLKS) {
    // Bm [E][2304][16] -> bmr [2304][128]
    long i0 = ((long)(b - XBLKS - WBLKS - ABLKS) * 256 + tid) * 8;
    u16 v[8];
#pragma unroll
    for (int j = 0; j < 8; ++j) {
      long idx = i0 + j;
      long o = idx >> 7, er = idx & 127;
      long e = er >> 4, r = er & 15;
      v[j] = f2b(ldf(Bm, (e * 2304 + o) * 16 + r, f32));
    }
    *(uint4*)&bmr[i0] = *(uint4*)v;
  } else {
    // gate: gsc[bb*8+e] = softmax_e(z[bb,:].Wg[e,:] + bg[e]) * SCALING
    if (tid == 0) *flagp = s_flag;
    if (tid < 64) {
      const int bb = tid >> 3, e = tid & 7;
      float acc = ldf(bg, e, f32);
      for (int i = 0; i < 64; ++i)
        acc += ldf(z, bb * 64 + i, f32) * ldf(Wg, e * 64 + i, f32);
      float mx = acc;
      for (int off = 1; off < 8; off <<= 1) mx = fmaxf(mx, __shfl_xor(mx, off, 64));
      float ex = __expf(acc - mx);
      float sm = ex;
      for (int off = 1; off < 8; off <<= 1) sm += __shfl_xor(sm, off, 64);
      gsc[tid] = (ex / sm) * SCALING;
    }
  }
}

// ---- gemm_h: hg[m, e*16+r] = (x @ A^T)[m,er] * gsc[batch(m)*8+e] ----
// M=16384, N=128, K=768; BM=64 tile (256 blocks -> all 256 CUs busy;
// the old 128-tile grid of 128 blocks left half the chip idle). bf16 out.
__global__ __launch_bounds__(256) void gemm_h(
    const u16* __restrict__ xbf, const u16* __restrict__ Abf,
    const float* __restrict__ gsc, u16* __restrict__ hg) {
  __shared__ __align__(128) u16 As[64][64];
  __shared__ __align__(128) u16 Bs[128][64];
  const int tid = threadIdx.x, wave = tid >> 6, lane = tid & 63;
  const int wm = wave >> 1, wn = wave & 1;       // 2m x 2n waves, wave-tile 32x64
  const int quad = lane >> 4, l16 = lane & 15;
  const int srow = lane >> 3, scol = (lane & 7) * 8;
  const int m0 = blockIdx.x * 64;

  floatx4 acc[2][4];
#pragma unroll
  for (int i = 0; i < 2; ++i)
#pragma unroll
    for (int j = 0; j < 4; ++j) acc[i][j] = floatx4{0.f, 0.f, 0.f, 0.f};

  for (int kb = 0; kb < 12; ++kb) {
    const int kc = kb * 64;
    // A: 64 rows; each wave stages rows [wave*16, wave*16+16)
#pragma unroll
    for (int j = 0; j < 2; ++j) {
      int r = wave * 16 + j * 8 + srow;
      gload_lds16(xbf + (size_t)(m0 + r) * KX + kc + scol,
                  (char*)(&As[0][0]) + (wave * 16 + j * 8) * 128);
    }
    // B: 128 rows of Abf
#pragma unroll
    for (int j = 0; j < 4; ++j) {
      int r = wave * 32 + j * 8 + srow;
      gload_lds16(Abf + (size_t)r * KX + kc + scol,
                  (char*)(&Bs[0][0]) + (wave * 32 + j * 8) * 128);
    }
    __syncthreads();
#pragma unroll
    for (int ks = 0; ks < 2; ++ks) {
      short8 af[2], bf[4];
#pragma unroll
      for (int mi = 0; mi < 2; ++mi)
        af[mi] = *(const short8*)&As[wm * 32 + mi * 16 + l16][ks * 32 + quad * 8];
#pragma unroll
      for (int ni = 0; ni < 4; ++ni)
        bf[ni] = *(const short8*)&Bs[wn * 64 + ni * 16 + l16][ks * 32 + quad * 8];
#pragma unroll
      for (int mi = 0; mi < 2; ++mi)
#pragma unroll
        for (int ni = 0; ni < 4; ++ni)
          acc[mi][ni] = __builtin_amdgcn_mfma_f32_16x16x32_bf16(af[mi], bf[ni], acc[mi][ni], 0, 0, 0);
    }
    __syncthreads();
  }
  // epilogue: scale by gate; e = col>>4 = wn*4+ni (col-block 16 = one expert)
  const int bb = m0 >> 11;
  float gv[4];
#pragma unroll
  for (int ni = 0; ni < 4; ++ni) gv[ni] = gsc[bb * 8 + wn * 4 + ni];
#pragma unroll
  for (int mi = 0; mi < 2; ++mi) {
    int rbase = m0 + wm * 32 + mi * 16 + quad * 4;
#pragma unroll
    for (int ni = 0; ni < 4; ++ni) {
      int c = wn * 64 + ni * 16 + l16;
#pragma unroll
      for (int t = 0; t < 4; ++t)
        hg[(size_t)(rbase + t) * KL + c] = f2b(acc[mi][ni][t] * gv[ni]);
    }
  }
}

// ---- gemm_main: out = [x | hg] @ [W | bmr]^T + b ; M=16384 N=2304 K=896 ----
// R0-proven 2-phase 128x128 structure. Changes vs R0 (both L2-targeted):
//  1. occupancy capped at 4 blocks/CU via 8KB LDS pad (was 5): shrinks the
//     per-XCD co-resident tile window; m114 says ~3 blocks/CU already gives
//     full MFMA+VALU overlap, so latency hiding is preserved.
//  2. supertile ordering within each XCD (8m x 3n, ST_n-fastest): keeps the
//     live window square-ish (~4.8MB vs 5.9MB), cutting L2 thrash; FETCH was
//     57.7MB = 2x the 29MB cold-input ideal.
__global__ __launch_bounds__(256) void gemm_main(
    const u16* __restrict__ xbf, const u16* __restrict__ hg,
    const u16* __restrict__ Wbf, const u16* __restrict__ bmr,
    const void* __restrict__ bias, void* __restrict__ outv,
    const int* __restrict__ flagp) {
  __shared__ __align__(128) u16 As[128][64];
  __shared__ __align__(128) u16 Bs[128][64];
  __shared__ u16 occ_pad[4096];   // 8KB: LDS 32->40KB caps blocks/CU at 4
  const int tid = threadIdx.x, wave = tid >> 6, lane = tid & 63;
  const int wm = wave >> 1, wn = wave & 1;
  const int quad = lane >> 4, l16 = lane & 15;
  const int srow = lane >> 3, scol = (lane & 7) * 8;

  // XCD swizzle + supertile order: 2304 blocks = 8 xcd * 288.
  // Per XCD: 16 m-tiles (= one batch: x-slice 3.1MB + hg 0.5MB) x 18 n-tiles.
  // ST = 8m x 3n (24 blocks), ST_n fastest; m-fastest inside the ST.
  const int linear = blockIdx.x;
  const int xcd = linear & 7;
  const int g = linear >> 3;            // 0..287
  const int st = g / 24;                // 0..11: st_n = st%6, st_m = st/6
  const int w  = g % 24;
  const int m_idx = xcd * 16 + (st / 6) * 8 + (w & 7);
  const int n_idx = (st % 6) * 3 + (w >> 3);
  const int m0 = m_idx * 128;
  const int n0 = n_idx * 128;
  if (tid == 0) ((volatile u16*)occ_pad)[0] = (u16)linear;  // keep pad alive

  floatx4 acc[4][4];
#pragma unroll
  for (int i = 0; i < 4; ++i)
#pragma unroll
    for (int j = 0; j < 4; ++j) acc[i][j] = floatx4{0.f, 0.f, 0.f, 0.f};

  for (int kb = 0; kb < 14; ++kb) {
    const u16* ap; const u16* bp; int lda, ldb, kc;
    if (kb < 12) { ap = xbf; lda = KX; bp = Wbf; ldb = KX; kc = kb * 64; }
    else         { ap = hg;  lda = KL; bp = bmr; ldb = KL; kc = (kb - 12) * 64; }
#pragma unroll
    for (int j = 0; j < 4; ++j) {
      int r = wave * 32 + j * 8 + srow;
      gload_lds16(ap + (size_t)(m0 + r) * lda + kc + scol,
                  (char*)(&As[0][0]) + (wave * 32 + j * 8) * 128);
      gload_lds16(bp + (size_t)(n0 + r) * ldb + kc + scol,
                  (char*)(&Bs[0][0]) + (wave * 32 + j * 8) * 128);
    }
    __syncthreads();
#pragma unroll
    for (int ks = 0; ks < 2; ++ks) {
      short8 af[4], bf[4];
#pragma unroll
      for (int mi = 0; mi < 4; ++mi)
        af[mi] = *(const short8*)&As[wm * 64 + mi * 16 + l16][ks * 32 + quad * 8];
#pragma unroll
      for (int ni = 0; ni < 4; ++ni)
        bf[ni] = *(const short8*)&Bs[wn * 64 + ni * 16 + l16][ks * 32 + quad * 8];
#pragma unroll
      for (int mi = 0; mi < 4; ++mi)
#pragma unroll
        for (int ni = 0; ni < 4; ++ni)
          acc[mi][ni] = __builtin_amdgcn_mfma_f32_16x16x32_bf16(af[mi], bf[ni], acc[mi][ni], 0, 0, 0);
    }
    __syncthreads();
  }

  // epilogue: C/D row = quad*4+t, col = l16 (m89/m91). Nontemporal stores:
  // output is write-once, never re-read -> avoid read-for-ownership fetch.
  const bool f32 = (*flagp != 0);
  float bv[4];
#pragma unroll
  for (int ni = 0; ni < 4; ++ni)
    bv[ni] = ldf(bias, n0 + wn * 64 + ni * 16 + l16, f32);
#pragma unroll
  for (int mi = 0; mi < 4; ++mi) {
    int rbase = m0 + wm * 64 + mi * 16 + quad * 4;
#pragma unroll
    for (int ni = 0; ni < 4; ++ni) {
      int c = n0 + wn * 64 + ni * 16 + l16;
#pragma unroll
      for (int t = 0; t < 4; ++t) {
        float v = acc[mi][ni][t] + bv[ni];
        size_t idx = (size_t)(rbase + t) * N_OUT + c;
        if (f32) __builtin_nontemporal_store(v, (float*)outv + idx);
        else     __builtin_nontemporal_store(f2b(v), (u16*)outv + idx);
      }
    }
  }
}

extern "C" void kernel_launch(void* const* d_in, const int* in_sizes, int n_in,
                              void* d_out, int out_size, void* d_ws, size_t ws_size,
                              hipStream_t stream) {
  // setup order: x, z, W, b, A, Bm, Wg, bg
  const void* x  = d_in[0];
  const void* z  = d_in[1];
  const void* W  = d_in[2];
  const void* bb = d_in[3];
  const void* A  = d_in[4];
  const void* Bm = d_in[5];
  const void* Wg = d_in[6];
  const void* bg = d_in[7];

  char* ws = (char*)d_ws;
  int*   flag = (int*)ws;
  float* gsc  = (float*)(ws + 256);
  u16*   xbf  = (u16*)(ws + 1024);                                   // 16384*768
  u16*   Wbf  = (u16*)(ws + 1024 + 25165824ull);                     // 2304*768
  u16*   Abf  = (u16*)(ws + 1024 + 25165824ull + 3538944ull);        // 128*768
  u16*   bmr  = (u16*)(ws + 1024 + 25165824ull + 3538944ull + 196608ull);
  u16*   hg   = (u16*)(ws + 1024 + 25165824ull + 3538944ull + 196608ull + 589824ull);

  prep_kernel<<<PREP_BLOCKS, 256, 0, stream>>>(
      x, W, A, Bm, z, Wg, bg, xbf, Wbf, Abf, bmr, gsc, flag);

  gemm_h<<<M_TOT / 64, 256, 0, stream>>>(xbf, Abf, gsc, hg);

  gemm_main<<<(N_OUT / 128) * (M_TOT / 128), 256, 0, stream>>>(
      xbf, hg, Wbf, bmr, bb, d_out, flag);
}